// Round 11
// baseline (209.624 us; speedup 1.0000x reference)
//
#include <hip/hip_runtime.h>

// CRF NLL on MI355X, round 13: DUAL-STREAM 1024-thread block — fwd on waves
// 0-7, bwd on waves 8-15, each group running the PROVEN r7 per-lane geometry
// (64 teams x 8 subs, 2 cols/team, 16-row slice; 16 pk-FMA, red8, 2 expf).
// One shared barrier per interval advances BOTH streams one step: the fixed
// cost (barrier rendezvous + DS latency exposure) is paid once per interval,
// not once per stream-step. Grid = 128 blocks (half chip -> r3's faster
// clock regime). Evidence: r6 (2 streams on SAME lanes) = 655cy/stream vs
// r7 (1 stream/block) = 865 -> sharing fixed costs is worth ~200cy/stream;
// this round gets the sharing WITHOUT r6's serial VALU stacking.
// r12 lesson applied: keep r7's per-lane shape (its VALU-serial chain is the
// optimum); do NOT trade DS traffic for VALU. r8 lesson applied: ONE code
// path for both groups (unified stride arithmetic sR/sJ), no runtime-branch
// alloca init -> no CFG-merge scratch demotion; all barriers unconditional.
// Junction fused in-block (both final vectors co-resident); ws = 128 scalars.

#define BB   128
#define TT   512
#define CC   128
#define NTHR 1024
#define PF   4

typedef float v2f __attribute__((ext_vector_type(2)));

__device__ __forceinline__ void bar_nodrain() {
    // LDS-visibility barrier that does NOT drain vmcnt (global feats prefetch
    // stays in flight). "memory" clobber stops compiler reordering across it.
    asm volatile("s_waitcnt lgkmcnt(0)\n\ts_barrier" ::: "memory");
}

template<int CTRL>
__device__ __forceinline__ float dpp_xadd(float x) {
    const int y = __builtin_amdgcn_update_dpp(0, __float_as_int(x), CTRL, 0xF, 0xF, true);
    return x + __int_as_float(y);
}

// Sum across each aligned group of 8 lanes (team) at VALU speed.
__device__ __forceinline__ float red8(float x) {
    x = dpp_xadd<0xB1>(x);    // quad_perm(1,0,3,2): + lane^1
    x = dpp_xadd<0x4E>(x);    // quad_perm(2,3,0,1): + lane^2
    x = dpp_xadd<0x141>(x);   // row_half_mirror:    + lane^4 within each 8
    return x;
}

__global__ __launch_bounds__(NTHR) void crf_scan(
    const float* __restrict__ feats,
    const int*   __restrict__ mask,
    const int*   __restrict__ tags,
    const float* __restrict__ trans,
    float*       __restrict__ ws)    // ws[bb] = logZ_bb - gold_bb
{
    const int bb  = blockIdx.x;
    const int tid = threadIdx.x;
    const int grp = tid >> 9;        // 0 = fwd stream, 1 = bwd stream
    const int lt  = tid & 511;       // lane id within the stream group
    const int jp  = lt >> 3;         // team: columns 2jp, 2jp+1
    const int sub = lt & 7;          // 16-row slice of the reduction axis
    const int j0  = jp * 2;
    const int j1  = j0 + 1;
    const int wid = tid >> 6;        // 0..15
    const int base = bb * TT;

    __shared__ __align__(16) float bufF[2][CC];  // fwd ping-pong state
    __shared__ __align__(16) float bufB[2][CC];  // bwd ping-pong state
    __shared__ float wred[16];
    __shared__ int   iw[8];
    __shared__ float sbSB;

    // ---- group 0: mask popcounts (for len) + gold-score partials.
    //      No barriers inside this branch (barrier discipline: uniform). ----
    float gold = 0.0f;               // meaningful on tid==0 only
    if (grp == 0) {
        const int myM = mask[base + lt];
        const unsigned long long bal = __ballot(myM != 0);
        if ((lt & 63) == 0) iw[wid] = (int)__popcll(bal);
        float sc = 0.0f;
        if (myM) {
            const int tg = tags[base + lt];
            sc += feats[((size_t)(base + lt)) * CC + tg];
            sc += (lt == 0) ? trans[(CC - 2) * CC + tg]
                            : trans[tags[base + lt - 1] * CC + tg];
            const int nm = (lt == TT - 1) ? 0 : mask[base + lt + 1];
            if (!nm) sc += trans[tg * CC + (CC - 1)];
        }
        #pragma unroll
        for (int o = 1; o <= 32; o <<= 1) sc += __shfl_xor(sc, o);
        if ((lt & 63) == 0) wred[wid] = sc;
    }
    bar_nodrain();                   // iw, wred visible to all 16 waves

    int len = 0;
    #pragma unroll
    for (int w = 0; w < 8; ++w) len += iw[w];
    if (tid == 0) {
        float g = 0.0f;
        #pragma unroll
        for (int w = 0; w < 8; ++w) g += wred[w];
        gold = g;
    }

    // ---- E fragments (16 v2f = 32 VGPR, r7-proven size) via UNIFIED strides:
    //      fwd (sR=CC,sJ=1): E0v = exp(trans[r][j0]) column slices
    //      bwd (sR=1,sJ=CC): E0v = exp(trans[j0][r]) row slices
    //      kkA chunk swizzle keeps each wave's 8 16B buf-chunks on 8 bank quads.
    const int sR = grp ? 1 : CC;
    const int sJ = grp ? CC : 1;
    const int s2 = sub >> 1;
    int kkA[4];
    v2f E0v[8], E1v[8];
    #pragma unroll
    for (int k = 0; k < 4; ++k) {
        const int kk = (k + s2) & 3;
        kkA[k] = kk;
        const int r = sub * 16 + kk * 4;
        #pragma unroll
        for (int m = 0; m < 2; ++m) {
            const int r0 = r + 2 * m;
            v2f e0, e1;
            e0.x = __expf(trans[(size_t)r0 * sR + (size_t)j0 * sJ]);
            e0.y = __expf(trans[(size_t)(r0 + 1) * sR + (size_t)j0 * sJ]);
            e1.x = __expf(trans[(size_t)r0 * sR + (size_t)j1 * sJ]);
            e1.y = __expf(trans[(size_t)(r0 + 1) * sR + (size_t)j1 * sJ]);
            E0v[2 * k + m] = e0;
            E1v[2 * k + m] = e1;
        }
    }

    const float* fb = feats + (size_t)base * CC;
    const int M      = len >> 1;     // fwd steps
    const int nB     = len - M;      // bwd steps (>= 1, >= M)
    const int nSteps = grp ? nB : M;
    float (*mybuf)[CC] = grp ? bufB : bufF;

    // ---- init state: fwd a_0 = onehot(START);
    //      bwd c_0[j] = exp(trans[j][STOP]) * exp(f_{len-1}[j]) ----
    if (lt < CC) {
        float v;
        if (grp == 0) v = (lt == CC - 2) ? 1.0f : 0.0f;
        else          v = __expf(trans[(size_t)lt * CC + (CC - 1)])
                        * __expf(fb[(size_t)(len - 1) * CC + lt]);
        mybuf[0][lt] = v;
    }

    // ---- feats prefetch (PF deep): fwd walks up from 0, bwd down from len-2
    float2 fx[PF];
    #pragma unroll
    for (int k = 0; k < PF; ++k) {
        int tg = grp ? (len - 2 - k) : k;
        tg = (tg > 0) ? tg : 0;
        fx[k] = *(const float2*)&fb[(size_t)tg * CC + j0];
    }

    const float* pb0 = &mybuf[0][sub * 16];
    const float* pb1 = &mybuf[1][sub * 16];
    const float* pc  = &mybuf[1][0];         // rescale broadcast source

    float S = 0.0f;                  // sum of applied log(c), per stream
    const int nUp = (nB + 3) & ~3;   // nB >= M: uniform loop bound for block

    for (int tc = 0; tc < nUp; tc += 4) {
        #pragma unroll
        for (int k = 0; k < 4; ++k) {
            const int it  = tc + k;
            const int par = k & 1;   // == it & 1
            bar_nodrain();           // both groups' buf[par] now visible
            const float4* q = (const float4*)(par ? pb1 : pb0);
            float c = 1.0f;
            if (k == 3) c = pc[0];   // current state[0]; broadcast read

            v2f a0 = {0.f, 0.f}, a1 = {0.f, 0.f};
            v2f b0 = {0.f, 0.f}, b1 = {0.f, 0.f};
            #pragma unroll
            for (int kq = 0; kq < 4; ++kq) {
                const float4 P = q[kkA[kq]];
                v2f P01; P01.x = P.x; P01.y = P.y;
                v2f P23; P23.x = P.z; P23.y = P.w;
                a0 = __builtin_elementwise_fma(E0v[2 * kq],     P01, a0);
                a1 = __builtin_elementwise_fma(E0v[2 * kq + 1], P23, a1);
                b0 = __builtin_elementwise_fma(E1v[2 * kq],     P01, b0);
                b1 = __builtin_elementwise_fma(E1v[2 * kq + 1], P23, b1);
            }
            a0 += a1; b0 += b1;
            float s0 = red8(a0.x + a0.y);
            float s1 = red8(b0.x + b0.y);

            // emission factor; bwd's LAST step writes the raw matvec (its
            // premultiplier belongs to the fwd side -> each feat counted once)
            const bool noMul = (grp != 0) && (it == nSteps - 1);
            const float e0f = noMul ? 1.0f : __expf(fx[k].x);
            const float e1f = noMul ? 1.0f : __expf(fx[k].y);

            float v0, v1;
            if (k == 3) {            // deferred rescale by current state[0]
                const float rinv = __builtin_amdgcn_rcpf(c);
                v0 = e0f * s0 * rinv;
                v1 = e1f * s1 * rinv;
            } else {
                v0 = e0f * s0;
                v1 = e1f * s1;
            }

            // prefetch feats for step it+PF (clamped both ends; valid for
            // both directions; identical work per call)
            int tn = grp ? (len - 2 - (it + PF)) : (it + PF);
            tn = (tn > 0) ? tn : 0;
            tn = (tn < TT - 1) ? tn : (TT - 1);
            fx[k] = *(const float2*)&fb[(size_t)tn * CC + j0];

            if (it < nSteps) {       // uniform within each wave group
                if (k == 3) S += __logf(c);  // record exactly what was divided
                if (sub == 0) {
                    float2 w2; w2.x = v0; w2.y = v1;
                    *(float2*)&mybuf[par ^ 1][j0] = w2;
                }
            }
            // frozen steps: no write, no S update -> state stays exact.
        }
    }

    // ---- in-block junction: logZ = log(sum_j aM[j]*bM[j]) + SF + SB ----
    if (tid == 512) sbSB = S;        // bwd group's log-scale sum
    bar_nodrain();                   // all loop writes + sbSB visible
    float z = 0.0f;
    if (tid < CC) z = bufF[M & 1][tid] * bufB[nB & 1][tid];
    #pragma unroll
    for (int o = 1; o <= 32; o <<= 1) z += __shfl_xor(z, o);
    if ((tid & 63) == 0) wred[wid] = z;
    __syncthreads();
    if (tid == 0) {
        float zz = 0.0f;
        #pragma unroll
        for (int w = 0; w < 16; ++w) zz += wred[w];
        ws[bb] = __logf(zz) + S + sbSB - gold;   // S here is SF (tid0 is fwd)
    }
}

// Final: sum 128 per-batch NLL contributions, divide by B. One wave.
__global__ void crf_epi(const float* __restrict__ ws, float* __restrict__ out)
{
    const int lane = threadIdx.x;    // 0..63
    float r = ws[2 * lane] + ws[2 * lane + 1];
    #pragma unroll
    for (int o = 1; o <= 32; o <<= 1) r += __shfl_xor(r, o);
    if (lane == 0) out[0] = r * (1.0f / (float)BB);
}

extern "C" void kernel_launch(void* const* d_in, const int* in_sizes, int n_in,
                              void* d_out, int out_size, void* d_ws, size_t ws_size,
                              hipStream_t stream)
{
    const float* feats = (const float*)d_in[0];
    const int*   mask  = (const int*)d_in[1];
    const int*   tags  = (const int*)d_in[2];
    const float* trans = (const float*)d_in[3];
    float* out = (float*)d_out;
    float* ws  = (float*)d_ws;       // needs 128 floats

    crf_scan<<<BB, NTHR, 0, stream>>>(feats, mask, tags, trans, ws);
    crf_epi<<<1, 64, 0, stream>>>(ws, out);
}

// Round 12
// 169.190 us; speedup vs baseline: 1.2390x; 1.2390x over previous
//
#include <hip/hip_runtime.h>

// CRF NLL on MI355X, round 14: r7 structure + REGISTER-PINNED E fragments.
// Counter re-read across r3/r5/r7/r12/r13: VGPR_Count (36/64/40/40) is far
// below the E-fragment live set (32+ VGPR) -> the compiler has been
// REMATERIALIZING exp(trans) inside the scan loop every step (16 global
// L1-hit loads + 32 v_exp_f32 per lane per step), hidden inside the "865cy"
// step. Fix: E as 16 NAMED v2f (no arrays), unified-stride init (no CFG
// merge), then each component passed through asm volatile("" : "+v")
// once -> volatile asm can't be duplicated -> remat illegal -> RA must
// keep E live (~90 VGPR demand, well under the 256 cap; the r8-r11 RA
// refusals were all at >=128).
// Everything else r7/r8 verbatim (verified absmax 0 five times): 512 thr,
// 64 teams x 8 subs, fwd/bwd split across blocks (bb=bid>>1, dir=bid&1),
// kkA chunk-swizzled conflict-free LDS reads, DPP red8, deferred
// every-4-step rescale, PF=4 prefetch, no-drain barrier, per-batch ws
// slots (no atomics), fused junction+final epilogue. Added: trailing
// bar_nodrain before the ws write (closes r7's latent len==1 race).

#define BB   128
#define TT   512
#define CC   128
#define NTHR 512
#define PF   4
#define WS_STRIDE 320
// ws layout per batch bb at ws + 16 + bb*320:
//   [0:128) aM (fwd final)  [128:256) bM (bwd final)
//   [256] SF  [257] SB  [258] gold score
// total ws bytes: (16 + 128*320)*4 ~= 164 KB

typedef float v2f __attribute__((ext_vector_type(2)));

__device__ __forceinline__ void bar_nodrain() {
    // LDS-visibility barrier that does NOT drain vmcnt (global feats prefetch
    // stays in flight). "memory" clobber stops compiler reordering across it.
    asm volatile("s_waitcnt lgkmcnt(0)\n\ts_barrier" ::: "memory");
}

// Value barrier: forces x into a VGPR and makes its producer non-duplicable
// (volatile) -> the register allocator cannot rematerialize it per-iteration.
__device__ __forceinline__ float kreg(float x) {
    asm volatile("" : "+v"(x));
    return x;
}

template<int CTRL>
__device__ __forceinline__ float dpp_xadd(float x) {
    const int y = __builtin_amdgcn_update_dpp(0, __float_as_int(x), CTRL, 0xF, 0xF, true);
    return x + __int_as_float(y);
}

// Sum across each aligned group of 8 lanes (team) at VALU speed.
__device__ __forceinline__ float red8(float x) {
    x = dpp_xadd<0xB1>(x);    // quad_perm(1,0,3,2): + lane^1
    x = dpp_xadd<0x4E>(x);    // quad_perm(2,3,0,1): + lane^2
    x = dpp_xadd<0x141>(x);   // row_half_mirror:    + lane^4 within each 8
    return x;
}

__global__ __launch_bounds__(NTHR) void crf_scan(
    const float* __restrict__ feats,
    const int*   __restrict__ mask,
    const int*   __restrict__ tags,
    const float* __restrict__ trans,
    float*       __restrict__ ws)
{
    const int bb  = blockIdx.x >> 1;
    const int dir = blockIdx.x & 1;  // 0 = forward scan, 1 = backward scan
    const int tid = threadIdx.x;
    const int jp  = tid >> 3;        // team: columns 2jp, 2jp+1
    const int sub = tid & 7;         // 16-row slice of reduction axis
    const int j0  = jp * 2;
    const int j1  = j0 + 1;
    const int wid = tid >> 6;

    __shared__ __align__(16) float buf[2][CC];  // ping-pong state vector
    __shared__ float wred[8];

    // ---- sequence length (contiguous prefix mask; tid spans T exactly) ----
    const int myM = mask[bb * TT + tid];
    const int len = __syncthreads_count(myM);

    // ---- gold-path score (fwd block only; dir is block-uniform) ----
    if (dir == 0) {
        float sc = 0.0f;
        if (myM) {
            const int tg = tags[bb * TT + tid];
            sc += feats[((size_t)(bb * TT + tid)) * CC + tg];
            sc += (tid == 0) ? trans[(CC - 2) * CC + tg]
                             : trans[tags[bb * TT + tid - 1] * CC + tg];
            const int nm = (tid == TT - 1) ? 0 : mask[bb * TT + tid + 1];
            if (!nm) sc += trans[tg * CC + (CC - 1)];
        }
        #pragma unroll
        for (int o = 1; o <= 32; o <<= 1) sc += __shfl_xor(sc, o);
        if ((tid & 63) == 0) wred[wid] = sc;
        __syncthreads();
        if (tid == 0) {
            float s = 0.0f;
            #pragma unroll
            for (int k = 0; k < 8; ++k) s += wred[k];
            ws[16 + (size_t)bb * WS_STRIDE + 258] = s;
        }
    }

    // ---- E fragments: 16 NAMED v2f via unified strides.
    //  fwd (sR=CC,sJ=1): slot K holds exp(trans[r..r+3][j0/j1]) (col slices)
    //  bwd (sR=1,sJ=CC): slot K holds exp(trans[j0/j1][r..r+3]) (row slices)
    //  Slot K covers chunk cK=(K+s2)&3 of this sub's 16-row slice; the kkA
    //  stagger keeps each wave's 8 distinct 16B buf-chunks on 8 bank quads.
    const int sR = dir ? 1 : CC;
    const int sJ = dir ? CC : 1;
    const int s2 = sub >> 1;
    const int c0 = (0 + s2) & 3, c1 = (1 + s2) & 3;
    const int c2 = (2 + s2) & 3, c3 = (3 + s2) & 3;

    v2f Ea0, Eb0, Ec0, Ed0, Ea1, Eb1, Ec1, Ed1;
    v2f Ea2, Eb2, Ec2, Ed2, Ea3, Eb3, Ec3, Ed3;
#define INITE(K, CK) { \
    const int r = sub * 16 + (CK) * 4; \
    Ea##K.x = __expf(trans[(size_t)(r    ) * sR + (size_t)j0 * sJ]); \
    Ea##K.y = __expf(trans[(size_t)(r + 1) * sR + (size_t)j0 * sJ]); \
    Eb##K.x = __expf(trans[(size_t)(r + 2) * sR + (size_t)j0 * sJ]); \
    Eb##K.y = __expf(trans[(size_t)(r + 3) * sR + (size_t)j0 * sJ]); \
    Ec##K.x = __expf(trans[(size_t)(r    ) * sR + (size_t)j1 * sJ]); \
    Ec##K.y = __expf(trans[(size_t)(r + 1) * sR + (size_t)j1 * sJ]); \
    Ed##K.x = __expf(trans[(size_t)(r + 2) * sR + (size_t)j1 * sJ]); \
    Ed##K.y = __expf(trans[(size_t)(r + 3) * sR + (size_t)j1 * sJ]); }
    INITE(0, c0) INITE(1, c1) INITE(2, c2) INITE(3, c3)
#undef INITE
    // Pin all 32 components in registers (remat now illegal).
#define OPQ(K) { \
    Ea##K.x = kreg(Ea##K.x); Ea##K.y = kreg(Ea##K.y); \
    Eb##K.x = kreg(Eb##K.x); Eb##K.y = kreg(Eb##K.y); \
    Ec##K.x = kreg(Ec##K.x); Ec##K.y = kreg(Ec##K.y); \
    Ed##K.x = kreg(Ed##K.x); Ed##K.y = kreg(Ed##K.y); }
    OPQ(0) OPQ(1) OPQ(2) OPQ(3)
#undef OPQ

    const float* fb = feats + (size_t)(bb * TT) * CC;
    const int M      = len >> 1;     // fwd steps
    const int nB     = len - M;      // bwd steps (>= 1)
    const int nSteps = dir ? nB : M;

    // ---- init state: fwd a_0 = onehot(START);
    //      bwd c_0[j] = exp(trans[j][STOP]) * exp(f_{len-1}[j]) ----
    if (tid < CC) {
        float v;
        if (dir == 0) v = (tid == CC - 2) ? 1.0f : 0.0f;
        else          v = __expf(trans[(size_t)tid * CC + (CC - 1)])
                        * __expf(fb[(size_t)(len - 1) * CC + tid]);
        buf[0][tid] = v;
    }

    // ---- feats prefetch (PF deep): fwd walks up from 0, bwd down from len-2
    float2 fx[PF];
    #pragma unroll
    for (int k = 0; k < PF; ++k) {
        int tg = dir ? (len - 2 - k) : k;
        tg = (tg > 0) ? tg : 0;
        fx[k] = *(const float2*)&fb[(size_t)tg * CC + j0];
    }

    const float4* pb0c = (const float4*)&buf[0][sub * 16];
    const float4* pb1c = (const float4*)&buf[1][sub * 16];

    float S = 0.0f;                  // sum of applied log(c)
    const int nUp = (nSteps + 3) & ~3;

    for (int tc = 0; tc < nUp; tc += 4) {
        #pragma unroll
        for (int k = 0; k < 4; ++k) {
            const int it  = tc + k;
            const int par = k & 1;   // == it & 1
            bar_nodrain();           // buf[par] now visible
            const float4* qb = par ? pb1c : pb0c;
            float c = 1.0f;
            if (k == 3) c = buf[1][0];   // current state[0]; broadcast read

            const float4 P0 = qb[c0];
            const float4 P1 = qb[c1];
            const float4 P2 = qb[c2];
            const float4 P3 = qb[c3];

            v2f a0 = {0.f, 0.f}, a1 = {0.f, 0.f};
            v2f b0 = {0.f, 0.f}, b1 = {0.f, 0.f};
#define DOT(K, P) { \
            v2f U01; U01.x = (P).x; U01.y = (P).y; \
            v2f U23; U23.x = (P).z; U23.y = (P).w; \
            a0 = __builtin_elementwise_fma(Ea##K, U01, a0); \
            a1 = __builtin_elementwise_fma(Eb##K, U23, a1); \
            b0 = __builtin_elementwise_fma(Ec##K, U01, b0); \
            b1 = __builtin_elementwise_fma(Ed##K, U23, b1); }
            DOT(0, P0) DOT(1, P1) DOT(2, P2) DOT(3, P3)
#undef DOT
            a0 += a1; b0 += b1;
            float s0 = red8(a0.x + a0.y);
            float s1 = red8(b0.x + b0.y);

            // emission factor; bwd's LAST step writes the raw matvec (its
            // premultiplier belongs to the fwd side -> each feat counted once)
            const bool noMul = (dir != 0) && (it == nSteps - 1);
            const float e0f = noMul ? 1.0f : __expf(fx[k].x);
            const float e1f = noMul ? 1.0f : __expf(fx[k].y);

            float v0, v1;
            if (k == 3) {            // deferred rescale by current state[0]
                const float rinv = __builtin_amdgcn_rcpf(c);
                v0 = e0f * s0 * rinv;
                v1 = e1f * s1 * rinv;
            } else {
                v0 = e0f * s0;
                v1 = e1f * s1;
            }

            // prefetch feats for step it+PF (clamped both ends; identical
            // work per call, valid for both directions)
            int tn = dir ? (len - 2 - (it + PF)) : (it + PF);
            tn = (tn > 0) ? tn : 0;
            tn = (tn < TT - 1) ? tn : (TT - 1);
            fx[k] = *(const float2*)&fb[(size_t)tn * CC + j0];

            if (it < nSteps) {       // uniform branch
                if (k == 3) S += __logf(c);  // record exactly what was divided
                if (sub == 0) {
                    float2 w2; w2.x = v0; w2.y = v1;
                    *(float2*)&buf[par ^ 1][j0] = w2;
                }
            }
            // frozen steps: no write, no S update -> state stays exact.
        }
    }

    // ---- write final vector + log-scale sum to workspace ----
    bar_nodrain();                   // init/loop writes visible (covers len==1)
    float* resv = ws + 16 + (size_t)bb * WS_STRIDE + dir * 128;
    if (sub == 0) {
        const float2 uu = *(const float2*)&buf[nSteps & 1][j0];
        *(float2*)&resv[j0] = uu;    // 64 teams cover all 128 cols
    }
    if (tid == 0) ws[16 + (size_t)bb * WS_STRIDE + 256 + dir] = S;
}

// Fused junction + final: one wave; thread handles 2 batch elements.
// r_b = log(sum_i aM[i]*bM[i]) + SF + SB - gold;  out = sum_b r_b / B.
__global__ void crf_epi(const float* __restrict__ ws, float* __restrict__ out)
{
    const int lane = threadIdx.x;    // 0..63
    float r = 0.0f;
    #pragma unroll
    for (int h = 0; h < 2; ++h) {
        const int b = lane * 2 + h;
        const float* base = ws + 16 + (size_t)b * WS_STRIDE;
        float dot = 0.0f;
        #pragma unroll 8
        for (int i = 0; i < 128; i += 4) {
            const float4 av = *(const float4*)&base[i];
            const float4 bv = *(const float4*)&base[128 + i];
            dot += av.x * bv.x + av.y * bv.y + av.z * bv.z + av.w * bv.w;
        }
        r += __logf(dot) + base[256] + base[257] - base[258];
    }
    #pragma unroll
    for (int o = 1; o <= 32; o <<= 1) r += __shfl_xor(r, o);
    if (lane == 0) out[0] = r * (1.0f / (float)BB);
}

extern "C" void kernel_launch(void* const* d_in, const int* in_sizes, int n_in,
                              void* d_out, int out_size, void* d_ws, size_t ws_size,
                              hipStream_t stream)
{
    const float* feats = (const float*)d_in[0];
    const int*   mask  = (const int*)d_in[1];
    const int*   tags  = (const int*)d_in[2];
    const float* trans = (const float*)d_in[3];
    float* out = (float*)d_out;
    float* ws  = (float*)d_ws;       // needs ~164 KB

    crf_scan<<<BB * 2, NTHR, 0, stream>>>(feats, mask, tags, trans, ws);
    crf_epi<<<1, 64, 0, stream>>>(ws, out);
}

// Round 13
// 163.506 us; speedup vs baseline: 1.2821x; 1.0348x over previous
//
#include <hip/hip_runtime.h>

// CRF NLL on MI355X, round 15: CONSOLIDATION at the measured optimum.
// = round-7 kernel (best total 166.77us) + r14's safety barrier before the
// final ws write (closes latent len==1 init-visibility race; measured free)
// + one chain micro-reassociation ((ef*rinv)*s: 1 dependent mul after red8
// on k==3 steps instead of 2).
// Session conclusion encoded here: the scan is DEPENDENCY-LATENCY bound
// (no counter >26% busy). Step ~790-865cy = 8-wave barrier + LDS-pipe
// instruction occupancy (32x ds_read_b128/CU/step, b128 = max width) +
// serial FMA/red8/exp/write chain. Bracketing experiments: 4/16 waves
// regress (r4,r13); 4col x 8row shape regresses (r12); register-resident E
// impossible >=128 VGPR (r8-11) and worthless when forced at low pressure
// (r14); stream-stacking regresses (r6,r13). Sequential depth floored at
// 256 (fwd/bwd 2-way split; deeper needs 128x128 matrix segments = 128x
// work). Structure: 256 blocks x 512 thr; bb=bid>>1, dir=bid&1; 64 teams
// x 8 subs; kkA bank-quad-staggered conflict-free LDS reads; DPP red8;
// deferred every-4-step rescale; PF=4 global prefetch under no-drain
// barriers; per-batch ws slots (no atomics); fused junction epilogue.

#define BB   128
#define TT   512
#define CC   128
#define NTHR 512
#define PF   4
#define WS_STRIDE 320
// ws layout per batch bb at ws + 16 + bb*320:
//   [0:128) aM (fwd final)  [128:256) bM (bwd final)
//   [256] SF  [257] SB  [258] gold score
// total ws bytes: (16 + 128*320)*4 ~= 164 KB

typedef float v2f __attribute__((ext_vector_type(2)));

__device__ __forceinline__ void bar_nodrain() {
    // LDS-visibility barrier that does NOT drain vmcnt (global feats prefetch
    // stays in flight). "memory" clobber stops compiler reordering across it.
    asm volatile("s_waitcnt lgkmcnt(0)\n\ts_barrier" ::: "memory");
}

template<int CTRL>
__device__ __forceinline__ float dpp_xadd(float x) {
    const int y = __builtin_amdgcn_update_dpp(0, __float_as_int(x), CTRL, 0xF, 0xF, true);
    return x + __int_as_float(y);
}

// Sum across each aligned group of 8 lanes (team) at VALU speed.
__device__ __forceinline__ float red8(float x) {
    x = dpp_xadd<0xB1>(x);    // quad_perm(1,0,3,2): + lane^1
    x = dpp_xadd<0x4E>(x);    // quad_perm(2,3,0,1): + lane^2
    x = dpp_xadd<0x141>(x);   // row_half_mirror:    + lane^4 within each 8
    return x;
}

__global__ __launch_bounds__(NTHR) void crf_scan(
    const float* __restrict__ feats,
    const int*   __restrict__ mask,
    const int*   __restrict__ tags,
    const float* __restrict__ trans,
    float*       __restrict__ ws)
{
    const int bb  = blockIdx.x >> 1;
    const int dir = blockIdx.x & 1;  // 0 = forward scan, 1 = backward scan
    const int tid = threadIdx.x;
    const int jp  = tid >> 3;        // team: columns 2jp, 2jp+1
    const int sub = tid & 7;         // 16-row slice of reduction axis
    const int j0  = jp * 2;
    const int j1  = j0 + 1;
    const int wid = tid >> 6;

    __shared__ __align__(16) float buf[2][CC];  // ping-pong state vector
    __shared__ float wred[8];

    // ---- sequence length (contiguous prefix mask; tid spans T exactly) ----
    const int myM = mask[bb * TT + tid];
    const int len = __syncthreads_count(myM);

    // ---- gold-path score (fwd block only; dir is block-uniform) ----
    if (dir == 0) {
        float sc = 0.0f;
        if (myM) {
            const int tg = tags[bb * TT + tid];
            sc += feats[((size_t)(bb * TT + tid)) * CC + tg];
            sc += (tid == 0) ? trans[(CC - 2) * CC + tg]
                             : trans[tags[bb * TT + tid - 1] * CC + tg];
            const int nm = (tid == TT - 1) ? 0 : mask[bb * TT + tid + 1];
            if (!nm) sc += trans[tg * CC + (CC - 1)];
        }
        #pragma unroll
        for (int o = 1; o <= 32; o <<= 1) sc += __shfl_xor(sc, o);
        if ((tid & 63) == 0) wred[wid] = sc;
        __syncthreads();
        if (tid == 0) {
            float s = 0.0f;
            #pragma unroll
            for (int k = 0; k < 8; ++k) s += wred[k];
            ws[16 + (size_t)bb * WS_STRIDE + 258] = s;
        }
    }

    // ---- fragments: fwd = E[r][j0/j1] row-pairs; bwd = E[j0/j1][r] col-pairs.
    //      kkA chunk swizzle keeps the wave's 8 16B buf-chunks on 8 bank quads.
    const int s2 = sub >> 1;
    int kkA[4];
    v2f F0v[8], F1v[8];
    #pragma unroll
    for (int k = 0; k < 4; ++k) {
        const int kk = (k + s2) & 3;
        kkA[k] = kk;
        const int r = sub * 16 + kk * 4;
        if (dir == 0) {
            #pragma unroll
            for (int m = 0; m < 2; ++m) {
                const int r0 = r + 2 * m;
                const float2 ta = *(const float2*)&trans[(size_t)(r0    ) * CC + j0];
                const float2 tb = *(const float2*)&trans[(size_t)(r0 + 1) * CC + j0];
                v2f e0, e1;
                e0.x = __expf(ta.x); e0.y = __expf(tb.x);
                e1.x = __expf(ta.y); e1.y = __expf(tb.y);
                F0v[2 * k + m] = e0;
                F1v[2 * k + m] = e1;
            }
        } else {
            const float4 u0 = *(const float4*)&trans[(size_t)j0 * CC + r];
            const float4 u1 = *(const float4*)&trans[(size_t)j1 * CC + r];
            v2f e;
            e.x = __expf(u0.x); e.y = __expf(u0.y); F0v[2 * k]     = e;
            e.x = __expf(u0.z); e.y = __expf(u0.w); F0v[2 * k + 1] = e;
            e.x = __expf(u1.x); e.y = __expf(u1.y); F1v[2 * k]     = e;
            e.x = __expf(u1.z); e.y = __expf(u1.w); F1v[2 * k + 1] = e;
        }
    }

    const float* fb = feats + (size_t)(bb * TT) * CC;
    const int M      = len >> 1;     // fwd steps
    const int nB     = len - M;      // bwd steps (>= 1)
    const int nSteps = dir ? nB : M;

    // ---- init state: fwd a_0 = onehot(START);
    //      bwd c_0[j] = exp(trans[j][STOP]) * exp(f_{len-1}[j]) ----
    if (tid < CC) {
        if (dir == 0) {
            buf[0][tid] = (tid == CC - 2) ? 1.0f : 0.0f;
        } else {
            buf[0][tid] = __expf(trans[(size_t)tid * CC + (CC - 1)])
                        * __expf(fb[(size_t)(len - 1) * CC + tid]);
        }
    }

    // ---- feats prefetch (PF deep): fwd walks t up from 0; bwd down from len-2
    float2 fx[PF];
    #pragma unroll
    for (int k = 0; k < PF; ++k) {
        int tg;
        if (dir == 0) tg = k;
        else { tg = len - 2 - k; tg = (tg > 0) ? tg : 0; }
        fx[k] = *(const float2*)&fb[(size_t)tg * CC + j0];
    }

    const float* pb0 = &buf[0][sub * 16];
    const float* pb1 = &buf[1][sub * 16];

    float S = 0.0f;                          // sum of applied log(c)
    const int nUp = (nSteps + 3) & ~3;       // may be 0 (fwd with len==1)

    for (int tc = 0; tc < nUp; tc += 4) {
        #pragma unroll
        for (int k = 0; k < 4; ++k) {
            const int it  = tc + k;
            const int par = k & 1;           // == it & 1
            bar_nodrain();                   // buf[par] now visible
            const float4* q = (const float4*)(par ? pb1 : pb0);
            float c = 1.0f;
            if (k == 3) c = buf[1][0];       // current state[0]; broadcast read

            v2f a0 = {0.f, 0.f}, a1 = {0.f, 0.f};
            v2f b0 = {0.f, 0.f}, b1 = {0.f, 0.f};
            #pragma unroll
            for (int kq = 0; kq < 4; ++kq) {
                const float4 P = q[kkA[kq]];
                v2f P01; P01.x = P.x; P01.y = P.y;
                v2f P23; P23.x = P.z; P23.y = P.w;
                a0 = __builtin_elementwise_fma(F0v[2 * kq],     P01, a0);
                a1 = __builtin_elementwise_fma(F0v[2 * kq + 1], P23, a1);
                b0 = __builtin_elementwise_fma(F1v[2 * kq],     P01, b0);
                b1 = __builtin_elementwise_fma(F1v[2 * kq + 1], P23, b1);
            }
            a0 += a1; b0 += b1;
            float s0 = red8(a0.x + a0.y);
            float s1 = red8(b0.x + b0.y);

            // emission factor (exps stay inside step k: keeps the global
            // prefetch a full PF=4 steps ahead of consumption).
            // bwd's LAST step writes the raw matvec (its premultiplier
            // belongs to the fwd side) so the junction counts each feat once.
            const bool noMul = (dir != 0) && (it == nSteps - 1);
            const float m0 = noMul ? 1.0f : __expf(fx[k].x);
            const float m1 = noMul ? 1.0f : __expf(fx[k].y);

            float v0, v1;
            if (k == 3) {
                // reassociated: (m*rinv) computable during red8 -> one
                // dependent mul after s0/s1 instead of two.
                const float rinv = __builtin_amdgcn_rcpf(c);
                const float e0m = m0 * rinv;
                const float e1m = m1 * rinv;
                v0 = e0m * s0;
                v1 = e1m * s1;
            } else {
                v0 = m0 * s0;
                v1 = m1 * s1;
            }

            // prefetch feats for step it+PF (clamped; identical work per call)
            int tn;
            if (dir == 0) { tn = it + PF;            tn = (tn < TT) ? tn : (TT - 1); }
            else          { tn = len - 2 - (it + PF); tn = (tn > 0) ? tn : 0; }
            fx[k] = *(const float2*)&fb[(size_t)tn * CC + j0];

            if (it < nSteps) {               // uniform branch
                if (k == 3) S += __logf(c);  // record exactly what was divided
                if (sub == 0) {
                    float2 w2; w2.x = v0; w2.y = v1;
                    *(float2*)&buf[par ^ 1][j0] = w2;
                }
            }
            // frozen steps: no writes, no S update -> state stays exact.
        }
    }

    // ---- write final vector + log-scale sum to workspace ----
    bar_nodrain();                   // init/loop writes visible (covers len==1)
    float* resv = ws + 16 + (size_t)bb * WS_STRIDE + dir * 128;
    if (sub == 0) {
        const float2 uu = *(const float2*)&buf[nSteps & 1][j0];
        *(float2*)&resv[j0] = uu;            // 64 teams cover all 128 cols
    }
    if (tid == 0) ws[16 + (size_t)bb * WS_STRIDE + 256 + dir] = S;
}

// Fused junction + final: one wave; thread handles 2 batch elements.
// r_b = log(sum_i aM[i]*bM[i]) + SF + SB - gold;  out = sum_b r_b / B.
__global__ void crf_epi(const float* __restrict__ ws, float* __restrict__ out)
{
    const int lane = threadIdx.x;    // 0..63
    float r = 0.0f;
    #pragma unroll
    for (int h = 0; h < 2; ++h) {
        const int b = lane * 2 + h;
        const float* base = ws + 16 + (size_t)b * WS_STRIDE;
        float dot = 0.0f;
        #pragma unroll 8
        for (int i = 0; i < 128; i += 4) {
            const float4 av = *(const float4*)&base[i];
            const float4 bv = *(const float4*)&base[128 + i];
            dot += av.x * bv.x + av.y * bv.y + av.z * bv.z + av.w * bv.w;
        }
        r += __logf(dot) + base[256] + base[257] - base[258];
    }
    #pragma unroll
    for (int o = 1; o <= 32; o <<= 1) r += __shfl_xor(r, o);
    if (lane == 0) out[0] = r * (1.0f / (float)BB);
}

extern "C" void kernel_launch(void* const* d_in, const int* in_sizes, int n_in,
                              void* d_out, int out_size, void* d_ws, size_t ws_size,
                              hipStream_t stream)
{
    const float* feats = (const float*)d_in[0];
    const int*   mask  = (const int*)d_in[1];
    const int*   tags  = (const int*)d_in[2];
    const float* trans = (const float*)d_in[3];
    float* out = (float*)d_out;
    float* ws  = (float*)d_ws;       // needs ~164 KB

    crf_scan<<<BB * 2, NTHR, 0, stream>>>(feats, mask, tags, trans, ws);
    crf_epi<<<1, 64, 0, stream>>>(ws, out);
}